// Round 1
// baseline (118.384 us; speedup 1.0000x reference)
//
#include <hip/hip_runtime.h>

#define BB 128
#define NN 16384
#define CC 8
#define WW 10
#define DD 3
#define LL 16375     // N - W + 1
#define LP 16392     // zero-padded weight length (covers l up to N-1)
#define SEG 8
#define CHUNKS 32
#define CHLEN 64     // (NN/SEG)/CHUNKS

// ---------------------------------------------------------------------------
// K0: build w2t[l][c] = (wr[c,l], wi[c,l]) interleaved, zero-padded l in [LL,LP)
// ---------------------------------------------------------------------------
__global__ __launch_bounds__(256) void k_interleave(const float* __restrict__ wr,
                                                    const float* __restrict__ wi,
                                                    float* __restrict__ w2) {
  int idx = blockIdx.x * 256 + threadIdx.x;   // idx = l*8 + c
  if (idx >= LP * CC) return;
  int l = idx >> 3;
  int c = idx & 7;
  float a = 0.f, b = 0.f;
  if (l < LL) { a = wr[c * LL + l]; b = wi[c * LL + l]; }
  w2[2 * idx]     = a;
  w2[2 * idx + 1] = b;
}

// ---------------------------------------------------------------------------
// K1: main FIR. Grid = B*SEG blocks x 256 threads.
// Thread (c = tid&7, chunk = tid>>3) accumulates acc[w] over its 64 n's with a
// 16-slot sliding register window of weights. Block-reduces the 32 chunks.
// ---------------------------------------------------------------------------
__global__ __launch_bounds__(256) void k_fir(const float* __restrict__ x,
                                             const float* __restrict__ w2,
                                             float* __restrict__ fpart) {
  int b   = blockIdx.x >> 3;
  int seg = blockIdx.x & 7;
  int tid = threadIdx.x;
  int c     = tid & 7;
  int chunk = tid >> 3;
  int n0 = seg * (NN / SEG) + chunk * CHLEN;   // multiple of 16

  const float2* __restrict__ xp  = ((const float2*)x)  + (size_t)b * NN * CC + c; // xp[n*CC]
  const float2* __restrict__ wpt = ((const float2*)w2) + c;                        // wpt[l*CC]

  float2 acc[WW];
#pragma unroll
  for (int w = 0; w < WW; ++w) { acc[w].x = 0.f; acc[w].y = 0.f; }

  float2 ww[16];
#pragma unroll
  for (int s = 0; s < 16; ++s) { ww[s].x = 0.f; ww[s].y = 0.f; }
  // preload slots for l = n0-9 .. n0-1 (slot = l & 15); l<0 stays zero
#pragma unroll
  for (int j = 1; j <= 9; ++j) {
    int l = n0 - j;
    if (l >= 0) ww[(16 - j) & 15] = wpt[(size_t)l * CC];
  }

  for (int g = 0; g < CHLEN / 16; ++g) {
    int nb = n0 + g * 16;
#pragma unroll
    for (int u = 0; u < 16; ++u) {
      int n = nb + u;
      ww[u] = wpt[(size_t)n * CC];       // slot n&15 == u; padded rows make this safe
      float2 xv = xp[(size_t)n * CC];
#pragma unroll
      for (int w = 0; w < WW; ++w) {
        float2 wt = ww[(u - w + 16) & 15];
        acc[w].x += xv.x * wt.x;
        acc[w].y += xv.y * wt.y;
      }
    }
  }

  // block reduction over the 32 chunks
  __shared__ float red[256 * 20];
#pragma unroll
  for (int w = 0; w < WW; ++w) {
    red[tid * 20 + 2 * w]     = acc[w].x;
    red[tid * 20 + 2 * w + 1] = acc[w].y;
  }
  __syncthreads();
  if (tid < 160) {               // tid = (w*8 + c)*2 + ri
    int cc = (tid >> 1) & 7;
    int wv = tid >> 4;
    int ri = tid & 1;
    int k  = 2 * wv + ri;
    float s = 0.f;
    for (int ch = 0; ch < 32; ++ch) s += red[(ch * 8 + cc) * 20 + k];
    fpart[(size_t)blockIdx.x * 160 + tid] = s;
  }
}

// ---------------------------------------------------------------------------
// K1b: reduce the SEG partials -> fsum[b][w][c][ri]
// ---------------------------------------------------------------------------
__global__ __launch_bounds__(256) void k_reduce(const float* __restrict__ fpart,
                                                float* __restrict__ fsum) {
  int idx = blockIdx.x * 256 + threadIdx.x;   // 128*160 total
  if (idx >= BB * 160) return;
  int b = idx / 160;
  int r = idx - b * 160;
  float s = 0.f;
#pragma unroll
  for (int seg = 0; seg < SEG; ++seg)
    s += fpart[((size_t)b * SEG + seg) * 160 + r];
  fsum[idx] = s;
}

// ---------------------------------------------------------------------------
// K2: polynomial mixing + output projection + BatchNorm. One block, 1024 thr.
// Thread (b = tid>>3, c = tid&7).
// ---------------------------------------------------------------------------
__global__ __launch_bounds__(1024) void k_finalize(const float* __restrict__ fsum,
                                                   const float* __restrict__ wc,
                                                   const float* __restrict__ wor,
                                                   const float* __restrict__ woi,
                                                   const float* __restrict__ gamma,
                                                   const float* __restrict__ beta,
                                                   float* __restrict__ out) {
  int tid = threadIdx.x;
  int b = tid >> 3;
  int c = tid & 7;

  float o_r = 0.f, o_i = 0.f;
  for (int w = 0; w < WW; ++w) {
    const float* fw = fsum + ((size_t)b * WW + w) * CC * 2;
    float nl0 = 0.f, nl1 = 0.f;
    const float* wc0 = wc + ((size_t)c * 2 + 0) * 42;  // Wc[c,0,ri,j,d]
    const float* wc1 = wc + ((size_t)c * 2 + 1) * 42;  // Wc[c,1,ri,j,d]
#pragma unroll
    for (int j = 0; j < CC; ++j) {
      if (j == c) continue;
      int jj = j - (j > c ? 1 : 0);
      float r  = fw[2 * j];
      float im = fw[2 * j + 1];
      float pw0 = r + im;
      float pw1 = r * r + im * im;
      float pw2 = r * r * r + im * im * im;
      float pwv[3] = {pw0, pw1, pw2};
#pragma unroll
      for (int d = 0; d < DD; ++d) {
        float pr = pwv[d] * r;
        float pi = pwv[d] * im;
        nl0 += pr * wc0[jj * 3 + d] + pi * wc0[21 + jj * 3 + d];
        nl1 += pr * wc1[jj * 3 + d] + pi * wc1[21 + jj * 3 + d];
      }
    }
    o_r += nl0 * wor[c * WW + w];
    o_i += nl1 * woi[c * WW + w];
  }

  // ---- BatchNorm over axes (b, complex) per channel c ----
  __shared__ float obuf[BB][CC][2];
  obuf[b][c][0] = o_r;
  obuf[b][c][1] = o_i;

  float s  = o_r + o_i;
  float sq = o_r * o_r + o_i * o_i;
  // lanes with equal c differ in bits 3..5 of the lane id
  for (int m = 8; m < 64; m <<= 1) {
    s  += __shfl_xor(s, m);
    sq += __shfl_xor(sq, m);
  }
  __shared__ float ps[16][8], psq[16][8];
  int wave = tid >> 6, lane = tid & 63;
  if (lane < 8) { ps[wave][lane] = s; psq[wave][lane] = sq; }
  __syncthreads();

  __shared__ float mv[8], iv[8], bv[8];
  if (tid < 8) {
    float S = 0.f, Q = 0.f;
#pragma unroll
    for (int k = 0; k < 16; ++k) { S += ps[k][tid]; Q += psq[k][tid]; }
    float mean = S * (1.0f / 256.0f);
    float var  = Q * (1.0f / 256.0f) - mean * mean;
    mv[tid] = mean;
    iv[tid] = gamma[tid] * rsqrtf(var + 1e-5f);
    bv[tid] = beta[tid];
  }
  __syncthreads();

  out[((size_t)b * CC + c) * 2 + 0] = (obuf[b][c][0] - mv[c]) * iv[c] + bv[c];
  out[((size_t)b * CC + c) * 2 + 1] = (obuf[b][c][1] - mv[c]) * iv[c] + bv[c];
}

// ---------------------------------------------------------------------------
extern "C" void kernel_launch(void* const* d_in, const int* in_sizes, int n_in,
                              void* d_out, int out_size, void* d_ws, size_t ws_size,
                              hipStream_t stream) {
  const float* x   = (const float*)d_in[0];
  const float* wr  = (const float*)d_in[1];
  const float* wi  = (const float*)d_in[2];
  const float* wc  = (const float*)d_in[3];
  const float* wor = (const float*)d_in[4];
  const float* woi = (const float*)d_in[5];
  const float* gm  = (const float*)d_in[6];
  const float* bt  = (const float*)d_in[7];
  float* out = (float*)d_out;

  float* ws    = (float*)d_ws;
  float* w2    = ws;                                    // CC*LP*2 = 262272 f32
  float* fpart = w2 + (size_t)CC * LP * 2;              // B*SEG*160 = 163840 f32
  float* fsum  = fpart + (size_t)BB * SEG * 160;        // B*160 = 20480 f32

  k_interleave<<<dim3((LP * CC + 255) / 256), dim3(256), 0, stream>>>(wr, wi, w2);
  k_fir<<<dim3(BB * SEG), dim3(256), 0, stream>>>(x, w2, fpart);
  k_reduce<<<dim3((BB * 160 + 255) / 256), dim3(256), 0, stream>>>(fpart, fsum);
  k_finalize<<<dim3(1), dim3(1024), 0, stream>>>(fsum, wc, wor, woi, gm, bt, out);
}

// Round 2
// 46.466 us; speedup vs baseline: 2.5478x; 2.5478x over previous
//
#include <hip/hip_runtime.h>

#define BB 128
#define NN 16384
#define CC 8
#define WW 10
#define DD 3
#define LL 16375     // N - W + 1
#define LP 16392     // zero-padded weight length (covers l up to N-1)
#define SEG 8
#define CHUNKS 32
#define CHLEN 64     // (NN/SEG)/CHUNKS
#define BPB 16       // b per k_nonlin block
#define ABLK (BB / BPB)

// ---------------------------------------------------------------------------
// K0: build w2t[l][c] = (wr[c,l], wi[c,l]) interleaved, zero-padded l in [LL,LP)
// ---------------------------------------------------------------------------
__global__ __launch_bounds__(256) void k_interleave(const float* __restrict__ wr,
                                                    const float* __restrict__ wi,
                                                    float* __restrict__ w2) {
  int idx = blockIdx.x * 256 + threadIdx.x;   // idx = l*8 + c
  if (idx >= LP * CC) return;
  int l = idx >> 3;
  int c = idx & 7;
  float a = 0.f, b = 0.f;
  if (l < LL) { a = wr[c * LL + l]; b = wi[c * LL + l]; }
  w2[2 * idx]     = a;
  w2[2 * idx + 1] = b;
}

// ---------------------------------------------------------------------------
// K1: main FIR. Grid = B*SEG blocks x 256 threads.
// Thread (c = tid&7, chunk = tid>>3) accumulates acc[w] over its 64 n's with a
// 16-slot sliding register window of weights. Block-reduces the 32 chunks.
// ---------------------------------------------------------------------------
__global__ __launch_bounds__(256) void k_fir(const float* __restrict__ x,
                                             const float* __restrict__ w2,
                                             float* __restrict__ fpart) {
  int b   = blockIdx.x >> 3;
  int seg = blockIdx.x & 7;
  int tid = threadIdx.x;
  int c     = tid & 7;
  int chunk = tid >> 3;
  int n0 = seg * (NN / SEG) + chunk * CHLEN;   // multiple of 16

  const float2* __restrict__ xp  = ((const float2*)x)  + (size_t)b * NN * CC + c; // xp[n*CC]
  const float2* __restrict__ wpt = ((const float2*)w2) + c;                        // wpt[l*CC]

  float2 acc[WW];
#pragma unroll
  for (int w = 0; w < WW; ++w) { acc[w].x = 0.f; acc[w].y = 0.f; }

  float2 ww[16];
#pragma unroll
  for (int s = 0; s < 16; ++s) { ww[s].x = 0.f; ww[s].y = 0.f; }
  // preload slots for l = n0-9 .. n0-1 (slot = l & 15); l<0 stays zero
#pragma unroll
  for (int j = 1; j <= 9; ++j) {
    int l = n0 - j;
    if (l >= 0) ww[(16 - j) & 15] = wpt[(size_t)l * CC];
  }

  for (int g = 0; g < CHLEN / 16; ++g) {
    int nb = n0 + g * 16;
#pragma unroll
    for (int u = 0; u < 16; ++u) {
      int n = nb + u;
      ww[u] = wpt[(size_t)n * CC];       // slot n&15 == u; padded rows make this safe
      float2 xv = xp[(size_t)n * CC];
#pragma unroll
      for (int w = 0; w < WW; ++w) {
        float2 wt = ww[(u - w + 16) & 15];
        acc[w].x += xv.x * wt.x;
        acc[w].y += xv.y * wt.y;
      }
    }
  }

  // block reduction over the 32 chunks
  __shared__ float red[256 * 20];
#pragma unroll
  for (int w = 0; w < WW; ++w) {
    red[tid * 20 + 2 * w]     = acc[w].x;
    red[tid * 20 + 2 * w + 1] = acc[w].y;
  }
  __syncthreads();
  if (tid < 160) {               // tid = (w*8 + c)*2 + ri
    int cc = (tid >> 1) & 7;
    int wv = tid >> 4;
    int ri = tid & 1;
    int k  = 2 * wv + ri;
    float s = 0.f;
    for (int ch = 0; ch < 32; ++ch) s += red[(ch * 8 + cc) * 20 + k];
    fpart[(size_t)blockIdx.x * 160 + tid] = s;
  }
}

// ---------------------------------------------------------------------------
// K2: nonlin + output projection. Grid = 8 blocks x 256 threads.
// Block handles BPB=16 b's: fuses the seg-reduction (staged to LDS via float4),
// expands w_coeff into 48 per-thread registers (j==c slot zeroed, no branch),
// computes o[b][c][p], writes raw output + per-(block,c) BN partial sums.
// Thread map: b = tid>>4 (0..15), c = (tid>>1)&7, p = tid&1.
// ---------------------------------------------------------------------------
__global__ __launch_bounds__(256) void k_nonlin(const float* __restrict__ fpart,
                                                const float* __restrict__ wc,
                                                const float* __restrict__ wor,
                                                const float* __restrict__ woi,
                                                float* __restrict__ oraw,
                                                float* __restrict__ part) {
  __shared__ float sred[BPB][164];   // seg-reduced rows [b][w*16 + c*2 + ri], padded
  __shared__ float swc[704];         // w_coeff (672 used, padded for safe OOB-lane reads)
  __shared__ float swout[160];       // [p][c][w]

  int tid = threadIdx.x;
  int blk = blockIdx.x;
  int b0 = blk * BPB;

  for (int i = tid; i < 672; i += 256) swc[i] = wc[i];
  if (tid < 80) swout[tid] = wor[tid];
  else if (tid < 160) swout[tid] = woi[tid - 80];

  // stage + seg-reduce fpart -> sred. fpart float4 layout: [(b*8+seg)][40]
  {
    const float4* fp4 = (const float4*)fpart;
    for (int o4 = tid; o4 < BPB * 40; o4 += 256) {
      int bl = o4 / 40;
      int r4 = o4 - bl * 40;
      float4 s = {0.f, 0.f, 0.f, 0.f};
      size_t base = ((size_t)(b0 + bl) * 8) * 40 + r4;
#pragma unroll
      for (int seg = 0; seg < 8; ++seg) {
        float4 v = fp4[base + (size_t)seg * 40];
        s.x += v.x; s.y += v.y; s.z += v.z; s.w += v.w;
      }
      int r = r4 * 4;
      sred[bl][r] = s.x; sred[bl][r + 1] = s.y; sred[bl][r + 2] = s.z; sred[bl][r + 3] = s.w;
    }
  }
  __syncthreads();

  int b = tid >> 4;
  int c = (tid >> 1) & 7;
  int p = tid & 1;

  // expand weights to registers: wreg[j][ri][d], zero for j==c (static indexing)
  float wreg[8][2][3];
#pragma unroll
  for (int j = 0; j < 8; ++j) {
    int jj = j - (j > c ? 1 : 0);
    if (j == c) jj = 0;                       // keep index in-bounds; value zeroed below
#pragma unroll
    for (int ri = 0; ri < 2; ++ri)
#pragma unroll
      for (int d = 0; d < 3; ++d) {
        float v = swc[(c * 2 + p) * 42 + ri * 21 + jj * 3 + d];
        wreg[j][ri][d] = (j == c) ? 0.f : v;
      }
  }

  float o = 0.f;
  const float* wop = swout + p * 80 + c * 10;
#pragma unroll
  for (int w = 0; w < WW; ++w) {
    float4 f0 = *(const float4*)&sred[b][w * 16];
    float4 f1 = *(const float4*)&sred[b][w * 16 + 4];
    float4 f2 = *(const float4*)&sred[b][w * 16 + 8];
    float4 f3 = *(const float4*)&sred[b][w * 16 + 12];
    float fv[16] = {f0.x, f0.y, f0.z, f0.w, f1.x, f1.y, f1.z, f1.w,
                    f2.x, f2.y, f2.z, f2.w, f3.x, f3.y, f3.z, f3.w};
    float nl0 = 0.f, nl1 = 0.f, nl2 = 0.f;
#pragma unroll
    for (int j = 0; j < 8; ++j) {
      float r  = fv[2 * j];
      float im = fv[2 * j + 1];
      float r2 = r * r, i2 = im * im;
      float pw0 = r + im;
      float pw1 = r2 + i2;
      float pw2 = r2 * r + i2 * im;
      nl0 += (pw0 * r) * wreg[j][0][0] + (pw0 * im) * wreg[j][1][0];
      nl1 += (pw1 * r) * wreg[j][0][1] + (pw1 * im) * wreg[j][1][1];
      nl2 += (pw2 * r) * wreg[j][0][2] + (pw2 * im) * wreg[j][1][2];
    }
    o += (nl0 + nl1 + nl2) * wop[w];
  }

  oraw[((size_t)(b0 + b) * CC + c) * 2 + p] = o;

  // per-(block, c) partial sums for BN
  __shared__ float sval[256], ssq[256];
  sval[tid] = o;
  ssq[tid]  = o * o;
  __syncthreads();
  if (tid < 8) {
    float S = 0.f, Q = 0.f;
#pragma unroll
    for (int k = 0; k < 32; ++k) {
      int t = (k >> 1) * 16 + tid * 2 + (k & 1);   // b=(k>>1), c=tid, p=(k&1)
      S += sval[t];
      Q += ssq[t];
    }
    part[(blk * 8 + tid) * 2 + 0] = S;
    part[(blk * 8 + tid) * 2 + 1] = Q;
  }
}

// ---------------------------------------------------------------------------
// K3: BatchNorm finalize. 1 block x 256 threads.
// ---------------------------------------------------------------------------
__global__ __launch_bounds__(256) void k_bn(const float* __restrict__ oraw,
                                            const float* __restrict__ part,
                                            const float* __restrict__ gamma,
                                            const float* __restrict__ beta,
                                            float* __restrict__ out) {
  __shared__ float mv[8], iv[8], bv[8];
  int tid = threadIdx.x;
  if (tid < 8) {
    float S = 0.f, Q = 0.f;
#pragma unroll
    for (int blk = 0; blk < ABLK; ++blk) {
      S += part[(blk * 8 + tid) * 2 + 0];
      Q += part[(blk * 8 + tid) * 2 + 1];
    }
    float mean = S * (1.0f / 256.0f);
    float var  = Q * (1.0f / 256.0f) - mean * mean;
    mv[tid] = mean;
    iv[tid] = gamma[tid] * rsqrtf(var + 1e-5f);
    bv[tid] = beta[tid];
  }
  __syncthreads();
  for (int i = tid; i < BB * CC * 2; i += 256) {
    int c = (i >> 1) & 7;
    out[i] = (oraw[i] - mv[c]) * iv[c] + bv[c];
  }
}

// ---------------------------------------------------------------------------
extern "C" void kernel_launch(void* const* d_in, const int* in_sizes, int n_in,
                              void* d_out, int out_size, void* d_ws, size_t ws_size,
                              hipStream_t stream) {
  const float* x   = (const float*)d_in[0];
  const float* wr  = (const float*)d_in[1];
  const float* wi  = (const float*)d_in[2];
  const float* wc  = (const float*)d_in[3];
  const float* wor = (const float*)d_in[4];
  const float* woi = (const float*)d_in[5];
  const float* gm  = (const float*)d_in[6];
  const float* bt  = (const float*)d_in[7];
  float* out = (float*)d_out;

  float* ws    = (float*)d_ws;
  float* w2    = ws;                                    // CC*LP*2 = 262272 f32
  float* fpart = w2 + (size_t)CC * LP * 2;              // B*SEG*160 = 163840 f32
  float* oraw  = fpart + (size_t)BB * SEG * 160;        // 2048 f32
  float* part  = oraw + BB * CC * 2;                    // 128 f32

  k_interleave<<<dim3((LP * CC + 255) / 256), dim3(256), 0, stream>>>(wr, wi, w2);
  k_fir<<<dim3(BB * SEG), dim3(256), 0, stream>>>(x, w2, fpart);
  k_nonlin<<<dim3(ABLK), dim3(256), 0, stream>>>(fpart, wc, wor, woi, oraw, part);
  k_bn<<<dim3(1), dim3(256), 0, stream>>>(oraw, part, gm, bt, out);
}